// Round 1
// 5422.142 us; speedup vs baseline: 1.7269x; 1.7269x over previous
//
// Decoder_56530359550871 — round 2: recurrence restructure (9 -> 5 kernels/step)
//  * AMT = A @ MT precomputed once (q2 GEMM removed from loop);
//    scores = AMT . h1 + sb0 (sb0 = A.(Wk^T bq) + PAD mask, precomputed)
//  * gate-interleaved fused weights (n' = h*4+gate): GEMM+LSTM-cell fused in one
//    kernel (8-wave K-split, LDS reduce, in-block cell). h double-buffered.
//  * combpart+a3 merged: comb = [h1|summary] @ Wc^T (+bc) in one GEMM
//  * softmax+summary fused; dist stored transposed [t*64+b][s]
//  * Phase C epilogue fused: softmax+copy-scatter+log in one kernel
//    (values in registers, copy bins in LDS) -> 1 read + 1 write of logits
// k_gemm_big (Phase C GEMM) and col-3 log(EPS) behavior unchanged.

#include <hip/hip_runtime.h>
#include <stdint.h>
#include <math.h>

#define Td 64
#define Bd 64
#define Sd 256
#define Ed 512
#define Hd 1024
#define Vd 16000
#define G4 4096

typedef short v8s __attribute__((ext_vector_type(8)));
typedef float v4f __attribute__((ext_vector_type(4)));

__device__ __forceinline__ float b2f(unsigned short v) {
  union { unsigned int u; float f; } x; x.u = ((unsigned int)v) << 16; return x.f;
}
__device__ __forceinline__ unsigned short f2b(float f) {
  union { float f; unsigned int u; } x; x.f = f;
  unsigned int u = x.u + 0x7fffu + ((x.u >> 16) & 1u);
  return (unsigned short)(u >> 16);
}

// ---------------- Phase A kernels ----------------

__global__ __launch_bounds__(256) void k_f2b(const float* __restrict__ s,
                                             unsigned short* __restrict__ d, int n) {
  int i = blockIdx.x * 256 + threadIdx.x;
  if (i < n) d[i] = f2b(s[i]);
}

// fused gate-interleaved weight conversion: dst[n'][k], n' = h*4+gate,
// n = gate*1024+h ; k < Kih -> ih, else hh
__global__ __launch_bounds__(256) void k_cvtgate(const float* __restrict__ ih,
                                                 const float* __restrict__ hh,
                                                 unsigned short* __restrict__ dst,
                                                 int Kih, int Ktot) {
  int i = blockIdx.x * 256 + threadIdx.x;  // grid sized exactly 4096*Ktot/256
  int np = i / Ktot;
  int k = i - np * Ktot;
  int n = ((np & 3) << 10) + (np >> 2);
  float v = (k < Kih) ? ih[(size_t)n * Kih + k]
                      : hh[(size_t)n * (Ktot - Kih) + (k - Kih)];
  dst[i] = f2b(v);
}

__global__ __launch_bounds__(256) void k_embed(const int* __restrict__ tok,
                                               const float* __restrict__ ew,
                                               unsigned short* __restrict__ dst) {
  int i = blockIdx.x * 256 + threadIdx.x;  // T*B*E
  int e = i & (Ed - 1);
  int tb = i >> 9;
  dst[i] = f2b(ew[(size_t)tok[tb] * Ed + e]);
}

// MTT[k][n] = sum_j Wk[j,n] * Wq[j,k]  (transposed store of old MT)
__global__ __launch_bounds__(256) void k_mt(const float* __restrict__ Wk,
                                            const float* __restrict__ Wq,
                                            unsigned short* __restrict__ MTT) {
  __shared__ float sk[32][33], sq[32][33];
  int tx = threadIdx.x & 15, ty = threadIdx.x >> 4;
  int n0 = blockIdx.x * 32, k0 = blockIdx.y * 32;
  float a00 = 0, a01 = 0, a10 = 0, a11 = 0;
  for (int jc = 0; jc < 32; jc++) {
    __syncthreads();
    for (int i = threadIdx.x; i < 1024; i += 256) {
      int r = i >> 5, c = i & 31;
      sk[r][c] = Wk[(jc * 32 + r) * Hd + n0 + c];
      sq[r][c] = Wq[(jc * 32 + r) * Hd + k0 + c];
    }
    __syncthreads();
    for (int j = 0; j < 32; j++) {
      float kv0 = sk[j][tx], kv1 = sk[j][tx + 16];
      float qv0 = sq[j][ty], qv1 = sq[j][ty + 16];
      a00 += kv0 * qv0; a01 += kv0 * qv1; a10 += kv1 * qv0; a11 += kv1 * qv1;
    }
  }
  MTT[(k0 + ty) * Hd + n0 + tx]             = f2b(a00);
  MTT[(k0 + ty + 16) * Hd + n0 + tx]        = f2b(a01);
  MTT[(k0 + ty) * Hd + n0 + tx + 16]        = f2b(a10);
  MTT[(k0 + ty + 16) * Hd + n0 + tx + 16]   = f2b(a11);
}

// biasq[n] = sum_j bq[j] * Wk[j,n]
__global__ __launch_bounds__(256) void k_biasq(const float* __restrict__ bq,
                                               const float* __restrict__ Wk,
                                               float* __restrict__ biasq) {
  int n = blockIdx.x * 256 + threadIdx.x;
  float a = 0;
  for (int j = 0; j < 1024; j++) a += bq[j] * Wk[j * Hd + n];
  biasq[n] = a;
}

// sb0[s,b] = A[s,b,:].biasq + (PAD ? -1e9 : 0)
__global__ __launch_bounds__(256) void k_sb0(const unsigned short* __restrict__ Ab,
                                             const float* __restrict__ biasq,
                                             const int* __restrict__ atok,
                                             float* __restrict__ sb0) {
  int w = blockIdx.x * 4 + (threadIdx.x >> 6);
  int lane = threadIdx.x & 63;
  int s = w >> 6, b = w & 63;
  const unsigned short* ap = Ab + ((size_t)(s * 64 + b) << 10) + lane * 16;
  v8s a0 = *(const v8s*)ap, a1 = *(const v8s*)(ap + 8);
  float acc = 0;
#pragma unroll
  for (int j = 0; j < 8; j++) {
    acc += b2f((unsigned short)a0[j]) * biasq[lane * 16 + j];
    acc += b2f((unsigned short)a1[j]) * biasq[lane * 16 + 8 + j];
  }
  for (int off = 32; off; off >>= 1) acc += __shfl_xor(acc, off, 64);
  if (lane == 0) {
    if (atok[s * 64 + b] == 0) acc += -1e9f;
    sb0[s * 64 + b] = acc;
  }
}

// bsum[n'] = b_ih[n] + b_hh[n], gate-interleaved
__global__ __launch_bounds__(256) void k_bsum(const float* __restrict__ bih,
                                              const float* __restrict__ bhh,
                                              float* __restrict__ dst) {
  int i = blockIdx.x * 256 + threadIdx.x;  // 4096
  int n = ((i & 3) << 10) + (i >> 2);
  dst[i] = bih[n] + bhh[n];
}

__global__ __launch_bounds__(256) void k_init(const float* __restrict__ h0in,
                                              const float* __restrict__ c0in,
                                              unsigned short* __restrict__ h0b,
                                              unsigned short* __restrict__ h1b,
                                              float* __restrict__ c0f, float* __restrict__ c1f,
                                              unsigned short* __restrict__ feed0) {
  int i = blockIdx.x * 256 + threadIdx.x;  // B*H
  h0b[i] = f2b(h0in[i]);
  h1b[i] = f2b(h0in[Bd * Hd + i]);
  c0f[i] = c0in[i];
  c1f[i] = c0in[Bd * Hd + i];
  feed0[i] = 0;
}

// ---------------- fused skinny GEMM (+cell / +comb epilogue) ----------------
// M=64, N-tile=16, 8 waves split K. Weights row-major [Nout][ldw] (bf16).
struct GCArgs {
  const unsigned short *a0, *a1, *a2;  // A sources, row-major [64][l*]
  int l0, l1, l2;
  const unsigned short* W; int ldw;
  int cpw;             // K/32/8
  const float* bsum;   // cell: gate-interleaved bias[4096]; comb: bc[1024]
  float* c;            // cell state (mode 0)
  unsigned short* hout;  // h-out (mode 0) or comb-out (mode 1), [64][1024] bf16
  int mode;            // 0 = LSTM cell, 1 = bias+f2b
};

__global__ __launch_bounds__(512) void k_gc(GCArgs g) {
  __shared__ float red[8][64][17];
  int tid = threadIdx.x;
  int w = tid >> 6, lane = tid & 63, lq = lane >> 4, l16 = lane & 15;
  int n0 = blockIdx.x * 16;
  int c0 = w * g.cpw;

  v4f acc[4];
#pragma unroll
  for (int mi = 0; mi < 4; mi++) acc[mi] = 0;

  auto ldA = [&](int ci, v8s af[4]) {
    int kv = (c0 + ci) * 32;
    const unsigned short* ap; int ld, ko;
    if (kv < g.l0) { ap = g.a0; ld = g.l0; ko = kv; }
    else if (kv < g.l0 + g.l1) { ap = g.a1; ld = g.l1; ko = kv - g.l0; }
    else { ap = g.a2; ld = g.l2; ko = kv - g.l0 - g.l1; }
    const unsigned short* base = ap + ko + lq * 8 + l16 * ld;
#pragma unroll
    for (int mi = 0; mi < 4; mi++) af[mi] = *(const v8s*)(base + mi * 16 * ld);
  };
  auto ldB = [&](int ci, v8s& bf) {
    bf = *(const v8s*)(g.W + (size_t)(n0 + l16) * g.ldw + (c0 + ci) * 32 + lq * 8);
  };

  v8s afc[4], afn[4], bfc, bfn;
  ldA(0, afc); ldB(0, bfc);
  for (int ci = 0; ci < g.cpw; ci++) {
    if (ci + 1 < g.cpw) { ldA(ci + 1, afn); ldB(ci + 1, bfn); }
#pragma unroll
    for (int mi = 0; mi < 4; mi++)
      acc[mi] = __builtin_amdgcn_mfma_f32_16x16x32_bf16(afc[mi], bfc, acc[mi], 0, 0, 0);
#pragma unroll
    for (int i = 0; i < 4; i++) afc[i] = afn[i];
    bfc = bfn;
  }

#pragma unroll
  for (int mi = 0; mi < 4; mi++)
#pragma unroll
    for (int r = 0; r < 4; r++)
      red[w][mi * 16 + lq * 4 + r][l16] = acc[mi][r];
  __syncthreads();

  if (g.mode == 0) {
    if (tid < 256) {
      int b = tid & 63, hl = tid >> 6;  // hl in 0..3
      float gv[4];
#pragma unroll
      for (int gg = 0; gg < 4; gg++) {
        float s = g.bsum[n0 + hl * 4 + gg];
#pragma unroll
        for (int w8 = 0; w8 < 8; w8++) s += red[w8][b][hl * 4 + gg];
        gv[gg] = s;
      }
      float si = 1.f / (1.f + expf(-gv[0]));
      float sf = 1.f / (1.f + expf(-gv[1]));
      float so = 1.f / (1.f + expf(-gv[3]));
      int h = (n0 >> 2) + hl;
      int idx = (b << 10) + h;
      float cn = sf * g.c[idx] + si * tanhf(gv[2]);
      g.c[idx] = cn;
      g.hout[idx] = f2b(so * tanhf(cn));
    }
  } else {
    int b = tid & 63, nh = tid >> 6;  // nh in 0..7
#pragma unroll
    for (int r = 0; r < 2; r++) {
      int nl = nh * 2 + r;
      float s = g.bsum[n0 + nl];
#pragma unroll
      for (int w8 = 0; w8 < 8; w8++) s += red[w8][b][nl];
      g.hout[(b << 10) + n0 + nl] = f2b(s);
    }
  }
}

// ---------------- attention ----------------
__global__ __launch_bounds__(256) void k_scores(const unsigned short* __restrict__ AMT,
                                                const unsigned short* __restrict__ h1,
                                                const float* __restrict__ sb0,
                                                float* __restrict__ scores) {
  int w = blockIdx.x * 4 + (threadIdx.x >> 6);
  int lane = threadIdx.x & 63;
  int s = w >> 6, b = w & 63;
  const unsigned short* ap = AMT + ((size_t)(s * 64 + b) << 10) + lane * 16;
  const unsigned short* qp = h1 + (b << 10) + lane * 16;
  v8s a0 = *(const v8s*)ap, a1 = *(const v8s*)(ap + 8);
  v8s q0 = *(const v8s*)qp, q1 = *(const v8s*)(qp + 8);
  float acc = 0;
#pragma unroll
  for (int j = 0; j < 8; j++) {
    acc += b2f((unsigned short)a0[j]) * b2f((unsigned short)q0[j]);
    acc += b2f((unsigned short)a1[j]) * b2f((unsigned short)q1[j]);
  }
  for (int off = 32; off; off >>= 1) acc += __shfl_xor(acc, off, 64);
  if (lane == 0) scores[s * 64 + b] = acc + sb0[s * 64 + b];
}

// softmax + summary fused; 4 blocks per b (h-range 256 each); j==0 writes distT
__global__ __launch_bounds__(256) void k_ss(const float* __restrict__ scores,
                                            const unsigned short* __restrict__ Ab,
                                            float* __restrict__ dist_t,
                                            unsigned short* __restrict__ summb) {
  __shared__ float red[256];
  __shared__ float ds[256];
  int b = blockIdx.x >> 2, j = blockIdx.x & 3;
  int s = threadIdx.x;
  float x = scores[s * 64 + b];
  red[s] = x; __syncthreads();
  for (int off = 128; off; off >>= 1) { if (s < off) red[s] = fmaxf(red[s], red[s + off]); __syncthreads(); }
  float m = red[0];
  __syncthreads();
  float e = expf(x - m);
  red[s] = e; __syncthreads();
  for (int off = 128; off; off >>= 1) { if (s < off) red[s] += red[s + off]; __syncthreads(); }
  float d = e * (1.f / red[0]);
  ds[s] = d;
  if (j == 0) dist_t[b * 256 + s] = d;
  __syncthreads();
  int h = (j << 8) + s;
  const unsigned short* ap = Ab + ((size_t)b << 10) + h;
  float acc = 0;
  for (int s2 = 0; s2 < 256; s2++) acc += ds[s2] * b2f(ap[(size_t)s2 * 64 * Hd]);
  summb[b * Hd + h] = f2b(acc);
}

// ---------------- Phase A big GEMM: AMT = A @ MTT^T-convention ----------------
__global__ __launch_bounds__(256) void k_gemm_amt(const unsigned short* __restrict__ A,
                                                  const unsigned short* __restrict__ Bw,
                                                  unsigned short* __restrict__ C) {
  __shared__ unsigned short As[128 * 40], Bs[128 * 40];
  int tid = threadIdx.x;
  int mb = blockIdx.x * 128, nb = blockIdx.y * 128;
  int wv = tid >> 6, lane = tid & 63, lq = lane >> 4, l16 = lane & 15;
  int mo = (wv & 1) * 64, no = (wv >> 1) * 64;
  int srow = tid >> 1, sh = (tid & 1) * 16;
  v4f acc[4][4];
#pragma unroll
  for (int i = 0; i < 4; i++)
#pragma unroll
    for (int j = 0; j < 4; j++) acc[i][j] = 0;
  const unsigned short* gA = A + (size_t)(mb + srow) * Hd + sh;
  const unsigned short* gB = Bw + (size_t)(nb + srow) * Hd + sh;
  for (int kc = 0; kc < Hd / 32; kc++) {
    v8s a0 = *(const v8s*)(gA + kc * 32);
    v8s a1 = *(const v8s*)(gA + kc * 32 + 8);
    v8s b0 = *(const v8s*)(gB + kc * 32);
    v8s b1 = *(const v8s*)(gB + kc * 32 + 8);
    __syncthreads();
    *(v8s*)&As[srow * 40 + sh] = a0;
    *(v8s*)&As[srow * 40 + sh + 8] = a1;
    *(v8s*)&Bs[srow * 40 + sh] = b0;
    *(v8s*)&Bs[srow * 40 + sh + 8] = b1;
    __syncthreads();
    v8s af[4], bf[4];
#pragma unroll
    for (int i = 0; i < 4; i++) af[i] = *(const v8s*)&As[(mo + i * 16 + l16) * 40 + lq * 8];
#pragma unroll
    for (int j = 0; j < 4; j++) bf[j] = *(const v8s*)&Bs[(no + j * 16 + l16) * 40 + lq * 8];
#pragma unroll
    for (int i = 0; i < 4; i++)
#pragma unroll
      for (int j = 0; j < 4; j++)
        acc[i][j] = __builtin_amdgcn_mfma_f32_16x16x32_bf16(af[i], bf[j], acc[i][j], 0, 0, 0);
  }
#pragma unroll
  for (int i = 0; i < 4; i++)
#pragma unroll
    for (int j = 0; j < 4; j++)
#pragma unroll
      for (int r = 0; r < 4; r++) {
        int row = mb + mo + i * 16 + lq * 4 + r;
        int col = nb + no + j * 16 + l16;
        C[(size_t)row * Hd + col] = f2b(acc[i][j][r]);
      }
}

// ---------------- Phase C ----------------
__global__ __launch_bounds__(256) void k_gemm_big(const unsigned short* __restrict__ A,
                                                  const unsigned short* __restrict__ Bw,
                                                  const float* __restrict__ bias,
                                                  float* __restrict__ C) {
  __shared__ unsigned short As[128 * 40], Bs[128 * 40];
  int tid = threadIdx.x;
  int mb = blockIdx.x * 128, nb = blockIdx.y * 128;
  int wv = tid >> 6, lane = tid & 63, lq = lane >> 4, l16 = lane & 15;
  int mo = (wv & 1) * 64, no = (wv >> 1) * 64;
  int srow = tid >> 1, sh = (tid & 1) * 16;
  v4f acc[4][4];
#pragma unroll
  for (int i = 0; i < 4; i++)
#pragma unroll
    for (int j = 0; j < 4; j++) acc[i][j] = 0;
  const unsigned short* gA = A + (size_t)(mb + srow) * Hd + sh;
  const unsigned short* gB = Bw + (size_t)(nb + srow) * Hd + sh;
  for (int kc = 0; kc < Hd / 32; kc++) {
    v8s a0 = *(const v8s*)(gA + kc * 32);
    v8s a1 = *(const v8s*)(gA + kc * 32 + 8);
    v8s b0 = *(const v8s*)(gB + kc * 32);
    v8s b1 = *(const v8s*)(gB + kc * 32 + 8);
    __syncthreads();
    *(v8s*)&As[srow * 40 + sh] = a0;
    *(v8s*)&As[srow * 40 + sh + 8] = a1;
    *(v8s*)&Bs[srow * 40 + sh] = b0;
    *(v8s*)&Bs[srow * 40 + sh + 8] = b1;
    __syncthreads();
    v8s af[4], bf[4];
#pragma unroll
    for (int i = 0; i < 4; i++) af[i] = *(const v8s*)&As[(mo + i * 16 + l16) * 40 + lq * 8];
#pragma unroll
    for (int j = 0; j < 4; j++) bf[j] = *(const v8s*)&Bs[(no + j * 16 + l16) * 40 + lq * 8];
#pragma unroll
    for (int i = 0; i < 4; i++)
#pragma unroll
      for (int j = 0; j < 4; j++)
        acc[i][j] = __builtin_amdgcn_mfma_f32_16x16x32_bf16(af[i], bf[j], acc[i][j], 0, 0, 0);
  }
#pragma unroll
  for (int i = 0; i < 4; i++)
#pragma unroll
    for (int j = 0; j < 4; j++)
#pragma unroll
      for (int r = 0; r < 4; r++) {
        int row = mb + mo + i * 16 + lq * 4 + r;
        int col = nb + no + j * 16 + l16;
        C[(size_t)row * Vd + col] = acc[i][j][r] + bias[col];
      }
}

// fused softmax + copy-scatter + log: out_i = log((e_i + e3*scatter_i + EPS*S)/S)
#define VPT 32
__global__ __launch_bounds__(512) void k_epi(float* __restrict__ out,
                                             const float* __restrict__ distT,
                                             const int* __restrict__ atok) {
  __shared__ float bins[Vd];
  __shared__ float red[8];
  __shared__ float sh_e3;
  int row = blockIdx.x;  // t*64 + b
  int tid = threadIdx.x, w = tid >> 6, lane = tid & 63;
  float* p = out + (size_t)row * Vd;
  float ev[VPT];
  float mx = -1e30f;
#pragma unroll
  for (int j = 0; j < VPT; j++) {
    int col = j * 512 + tid;
    ev[j] = (col < Vd) ? p[col] : -1e30f;
    mx = fmaxf(mx, ev[j]);
  }
  for (int off = 32; off; off >>= 1) mx = fmaxf(mx, __shfl_xor(mx, off, 64));
  if (lane == 0) red[w] = mx;
  __syncthreads();
  float m = red[0];
#pragma unroll
  for (int i = 1; i < 8; i++) m = fmaxf(m, red[i]);
  __syncthreads();
  float sum = 0.f;
#pragma unroll
  for (int j = 0; j < VPT; j++) {
    int col = j * 512 + tid;
    float e = (col < Vd) ? expf(ev[j] - m) : 0.f;
    ev[j] = e;
    sum += e;
  }
  for (int off = 32; off; off >>= 1) sum += __shfl_xor(sum, off, 64);
  if (lane == 0) red[w] = sum;
  __syncthreads();
  float S = 0.f;
#pragma unroll
  for (int i = 0; i < 8; i++) S += red[i];
  if (tid == 3) sh_e3 = ev[0];  // e at col 3 (COPY)
  for (int i = tid; i < Vd; i += 512) bins[i] = 0.f;
  __syncthreads();
  if (tid < 256) {
    int s = tid, b = row & 63;
    float wv = distT[(size_t)row * Sd + s] * sh_e3;
    atomicAdd(&bins[atok[s * 64 + b]], wv);
  }
  __syncthreads();
  float lS = logf(S);
  float eS = 1e-7f * S;
#pragma unroll
  for (int j = 0; j < VPT; j++) {
    int col = j * 512 + tid;
    if (col < Vd)
      p[col] = (col == 3) ? logf(1e-7f) : (logf(ev[j] + bins[col] + eS) - lS);
  }
}

// ---------------- host launch ----------------

extern "C" void kernel_launch(void* const* d_in, const int* in_sizes, int n_in,
                              void* d_out, int out_size, void* d_ws, size_t ws_size,
                              hipStream_t stream) {
  (void)in_sizes; (void)out_size;
  if (n_in < 22) return;
  const int* ref_tokens   = (const int*)d_in[0];
  const int* att_tokens   = (const int*)d_in[1];
  const float* att_feat   = (const float*)d_in[2];
  const float* h0in       = (const float*)d_in[3];
  const float* c0in       = (const float*)d_in[4];
  const float* embed_w    = (const float*)d_in[5];
  const float* W_ih0      = (const float*)d_in[6];
  const float* W_hh0      = (const float*)d_in[7];
  const float* b_ih0      = (const float*)d_in[8];
  const float* b_hh0      = (const float*)d_in[9];
  const float* W_ih1      = (const float*)d_in[10];
  const float* W_hh1      = (const float*)d_in[11];
  const float* b_ih1      = (const float*)d_in[12];
  const float* b_hh1      = (const float*)d_in[13];
  const float* Wk         = (const float*)d_in[14];
  // d_in[15] = bk: dropped (softmax(axis=0)-invariant)
  const float* Wq         = (const float*)d_in[16];
  const float* bq         = (const float*)d_in[17];
  const float* Wc         = (const float*)d_in[18];
  const float* bc         = (const float*)d_in[19];
  const float* Wp         = (const float*)d_in[20];
  const float* bp         = (const float*)d_in[21];
  // d_in[22]/[23] = Wsp/bsp: dropped (softmax over singleton == 1)
  float* out = (float*)d_out;

  char* p = (char*)d_ws;
  auto alloc = [&](size_t bytes) -> char* {
    char* r = p; p += (bytes + 255) & ~(size_t)255; return r;
  };
  unsigned short* Wl0   = (unsigned short*)alloc((size_t)G4 * (Ed + 2 * Hd) * 2);
  unsigned short* Wl1   = (unsigned short*)alloc((size_t)G4 * 2 * Hd * 2);
  unsigned short* Wcb   = (unsigned short*)alloc((size_t)Hd * 2 * Hd * 2);
  unsigned short* Wpb   = (unsigned short*)alloc((size_t)Vd * Hd * 2);
  unsigned short* MTT   = (unsigned short*)alloc((size_t)Hd * Hd * 2);
  unsigned short* Aattb = (unsigned short*)alloc((size_t)Sd * Bd * Hd * 2);
  unsigned short* embb  = (unsigned short*)alloc((size_t)Td * Bd * Ed * 2);
  unsigned short* combb = (unsigned short*)alloc((size_t)Td * Bd * Hd * 2);
  float* distT          = (float*)alloc((size_t)Td * Bd * Sd * 4);
  float* sb0            = (float*)alloc((size_t)Sd * Bd * 4);
  float* biasq          = (float*)alloc((size_t)Hd * 4);
  float* bsum0          = (float*)alloc((size_t)G4 * 4);
  float* bsum1          = (float*)alloc((size_t)G4 * 4);
  unsigned short* h0buf[2];
  h0buf[0] = (unsigned short*)alloc((size_t)Bd * Hd * 2);
  h0buf[1] = (unsigned short*)alloc((size_t)Bd * Hd * 2);
  unsigned short* h1buf[2];
  h1buf[0] = (unsigned short*)alloc((size_t)Bd * Hd * 2);
  h1buf[1] = (unsigned short*)alloc((size_t)Bd * Hd * 2);
  float* c0f            = (float*)alloc((size_t)Bd * Hd * 4);
  float* c1f            = (float*)alloc((size_t)Bd * Hd * 4);
  unsigned short* feed0 = (unsigned short*)alloc((size_t)Bd * Hd * 2);
  float* scoresbuf      = (float*)alloc((size_t)Sd * Bd * 4);
  unsigned short* summb = (unsigned short*)alloc((size_t)Bd * Hd * 2);
  if ((size_t)(p - (char*)d_ws) > ws_size) return;

  // AMT (S*B x H bf16, 33.5 MB) aliases the output buffer: only live during the
  // recurrence; Phase C's k_gemm_big overwrites out afterwards.
  unsigned short* AMTb = (unsigned short*)out;

  // ---- Phase A ----
  k_cvtgate<<<G4 * (Ed + 2 * Hd) / 256, 256, 0, stream>>>(W_ih0, W_hh0, Wl0, Ed + Hd, Ed + 2 * Hd);
  k_cvtgate<<<G4 * 2 * Hd / 256, 256, 0, stream>>>(W_ih1, W_hh1, Wl1, Hd, 2 * Hd);
  k_f2b<<<Hd * 2 * Hd / 256, 256, 0, stream>>>(Wc, Wcb, Hd * 2 * Hd);
  k_f2b<<<Vd * Hd / 256, 256, 0, stream>>>(Wp, Wpb, Vd * Hd);
  k_f2b<<<Sd * Bd * Hd / 256, 256, 0, stream>>>(att_feat, Aattb, Sd * Bd * Hd);
  k_embed<<<Td * Bd * Ed / 256, 256, 0, stream>>>(ref_tokens, embed_w, embb);
  k_mt<<<dim3(32, 32), 256, 0, stream>>>(Wk, Wq, MTT);
  k_biasq<<<4, 256, 0, stream>>>(bq, Wk, biasq);
  k_sb0<<<Sd * Bd / 4, 256, 0, stream>>>(Aattb, biasq, att_tokens, sb0);
  k_gemm_amt<<<dim3(Sd * Bd / 128, Hd / 128), 256, 0, stream>>>(Aattb, MTT, AMTb);
  k_bsum<<<16, 256, 0, stream>>>(b_ih0, b_hh0, bsum0);
  k_bsum<<<16, 256, 0, stream>>>(b_ih1, b_hh1, bsum1);
  k_init<<<Bd * Hd / 256, 256, 0, stream>>>(h0in, c0in, h0buf[0], h1buf[0], c0f, c1f, feed0);

  // ---- recurrence: 5 kernels/step ----
  for (int t = 0; t < Td; t++) {
    int pr = t & 1;
    const unsigned short* emb_t = embb + (size_t)t * Bd * Ed;
    const unsigned short* feed = (t == 0) ? feed0 : combb + (size_t)(t - 1) * Bd * Hd;
    unsigned short* comb_t = combb + (size_t)t * Bd * Hd;
    float* dist_t = distT + (size_t)t * Bd * Sd;

    GCArgs g0{};  // gates0 = [emb|feed|h0] @ Wl0^T, fused cell -> h0', c0
    g0.a0 = emb_t; g0.l0 = Ed; g0.a1 = feed; g0.l1 = Hd; g0.a2 = h0buf[pr]; g0.l2 = Hd;
    g0.W = Wl0; g0.ldw = Ed + 2 * Hd; g0.cpw = 10; g0.bsum = bsum0;
    g0.c = c0f; g0.hout = h0buf[1 - pr]; g0.mode = 0;
    k_gc<<<G4 / 16, 512, 0, stream>>>(g0);

    GCArgs g1{};  // gates1 = [h0'|h1] @ Wl1^T, fused cell -> h1', c1
    g1.a0 = h0buf[1 - pr]; g1.l0 = Hd; g1.a1 = h1buf[pr]; g1.l1 = Hd;
    g1.a2 = h1buf[pr]; g1.l2 = Hd;
    g1.W = Wl1; g1.ldw = 2 * Hd; g1.cpw = 8; g1.bsum = bsum1;
    g1.c = c1f; g1.hout = h1buf[1 - pr]; g1.mode = 0;
    k_gc<<<G4 / 16, 512, 0, stream>>>(g1);

    k_scores<<<Sd * Bd / 4, 256, 0, stream>>>(AMTb, h1buf[1 - pr], sb0, scoresbuf);
    k_ss<<<Bd * 4, 256, 0, stream>>>(scoresbuf, Aattb, dist_t, summb);

    GCArgs gc{};  // comb = [h1'|summary] @ Wc^T + bc -> bf16 feed
    gc.a0 = h1buf[1 - pr]; gc.l0 = Hd; gc.a1 = summb; gc.l1 = Hd;
    gc.a2 = summb; gc.l2 = Hd;
    gc.W = Wcb; gc.ldw = 2 * Hd; gc.cpw = 8; gc.bsum = bc;
    gc.c = nullptr; gc.hout = comb_t; gc.mode = 1;
    k_gc<<<Hd / 16, 512, 0, stream>>>(gc);
  }

  // ---- Phase C ----
  k_gemm_big<<<dim3(32, 125), 256, 0, stream>>>(combb, Wpb, bp, out);
  k_epi<<<Td * Bd, 512, 0, stream>>>(out, distT, att_tokens);
}